// Round 3
// baseline (159.045 us; speedup 1.0000x reference)
//
#include <hip/hip_runtime.h>

// ---------------------------------------------------------------------------
// MixModel: out[n,3j+0] = u[3j]*reg[3j+1]+reg[0] + o1.x + o1.y*ua + o1.z*ub
//           out[n,3j+1] = u[3j+1]*reg[3j+2]+reg[0] + o2.x + o2.y*ua + o2.z*ub
//           out[n,3j+2] = u[3j+2]*reg[3j+3]+reg[0] + o3.x + o3.y*ub
// with m=(j+11)%12, p=(j+1)%12:
//   MLP1 in: { u[3m+1], u[3j], u[3j+1] }          (3->3->6->3)
//   MLP2 in: { u[3j], u[3j+1], u[3p] }            (3->3->6->3)
//   MLP3 in: { u[3j], u[3j+1], u[3p], u[3p+1] }   (4->4->6->2)
//   ua = u[3m+2], ub = u[3j+2]
//
// R3: rolling-window + phase-mini-loops.
//  - R1 (VGPR=136, 3 waves/SIMD, VALUBusy 37%): uu[36]+o[36] live -> latency-bound.
//  - R2 (launch_bounds(256,4)): compiler clamped VGPR=64 -> scratch spills
//    (WRITE 140->382 MB). Never force the tier; shrink live state instead.
//  - Here: per group of 4 j's load only 5 float4 (20-col window incl. wrap
//    halos), run the 3 MLP phases as separate 4-j mini-loops (each phase's
//    ~60 weights stay in SGPRs with 4x reuse), store 3 float4 immediately.
//    True live state ~70 regs; no launch_bounds.
// ---------------------------------------------------------------------------

__device__ __forceinline__ float relu_(float x) { return fmaxf(x, 0.0f); }

// MLP 3 -> 3 -> 6 -> 3 (w0:(3,3), w1:(6,3), w2:(3,6), row-major [out][in])
__device__ __forceinline__ void mlp_a(float x0, float x1, float x2,
                                      const float* __restrict__ w0, const float* __restrict__ b0,
                                      const float* __restrict__ w1, const float* __restrict__ b1,
                                      const float* __restrict__ w2, const float* __restrict__ b2,
                                      float& o0, float& o1, float& o2)
{
    float h0[3];
#pragma unroll
    for (int q = 0; q < 3; ++q)
        h0[q] = relu_(fmaf(x2, w0[q*3+2], fmaf(x1, w0[q*3+1], fmaf(x0, w0[q*3+0], b0[q]))));
    float h1[6];
#pragma unroll
    for (int q = 0; q < 6; ++q)
        h1[q] = relu_(fmaf(h0[2], w1[q*3+2], fmaf(h0[1], w1[q*3+1], fmaf(h0[0], w1[q*3+0], b1[q]))));
    float t[3];
#pragma unroll
    for (int q = 0; q < 3; ++q) {
        float a = b2[q];
#pragma unroll
        for (int i = 0; i < 6; ++i) a = fmaf(h1[i], w2[q*6+i], a);
        t[q] = a;
    }
    o0 = t[0]; o1 = t[1]; o2 = t[2];
}

// MLP 4 -> 4 -> 6 -> 2 (w0:(4,4), w1:(6,4), w2:(2,6))
__device__ __forceinline__ void mlp_b(float x0, float x1, float x2, float x3,
                                      const float* __restrict__ w0, const float* __restrict__ b0,
                                      const float* __restrict__ w1, const float* __restrict__ b1,
                                      const float* __restrict__ w2, const float* __restrict__ b2,
                                      float& o0, float& o1)
{
    float h0[4];
#pragma unroll
    for (int q = 0; q < 4; ++q)
        h0[q] = relu_(fmaf(x3, w0[q*4+3], fmaf(x2, w0[q*4+2], fmaf(x1, w0[q*4+1], fmaf(x0, w0[q*4+0], b0[q])))));
    float h1[6];
#pragma unroll
    for (int q = 0; q < 6; ++q)
        h1[q] = relu_(fmaf(h0[3], w1[q*4+3], fmaf(h0[2], w1[q*4+2], fmaf(h0[1], w1[q*4+1], fmaf(h0[0], w1[q*4+0], b1[q])))));
    float t[2];
#pragma unroll
    for (int q = 0; q < 2; ++q) {
        float a = b2[q];
#pragma unroll
        for (int i = 0; i < 6; ++i) a = fmaf(h1[i], w2[q*6+i], a);
        t[q] = a;
    }
    o0 = t[0]; o1 = t[1];
}

__global__ void mixmodel_kernel(
    const float* __restrict__ u, const float* __restrict__ reg,
    const float* __restrict__ w10, const float* __restrict__ b10,
    const float* __restrict__ w11, const float* __restrict__ b11,
    const float* __restrict__ w12, const float* __restrict__ b12,
    const float* __restrict__ w20, const float* __restrict__ b20,
    const float* __restrict__ w21, const float* __restrict__ b21,
    const float* __restrict__ w22, const float* __restrict__ b22,
    const float* __restrict__ w30, const float* __restrict__ b30,
    const float* __restrict__ w31, const float* __restrict__ b31,
    const float* __restrict__ w32, const float* __restrict__ b32,
    float* __restrict__ out, int n)
{
    const int tid = blockIdx.x * blockDim.x + threadIdx.x;
    if (tid >= n) return;

    const float4* __restrict__ u4 = reinterpret_cast<const float4*>(u + (size_t)tid * 36);
    float4* __restrict__ o4 = reinterpret_cast<float4*>(out + (size_t)tid * 36);
    const float r0 = reg[0];

#pragma unroll
    for (int g = 0; g < 3; ++g) {
        // ---- rolling window: cols 12g-4 .. 12g+15 (wrapped), W(k)=u[12g+k] ----
        float w_[20];
        {
            const int iprev = (3 * g + 8) % 9;   // wrap: g=0 -> f4 #8
            const int inext = (3 * g + 3) % 9;   // wrap: g=2 -> f4 #0
            float4 v;
            v = u4[iprev];   w_[0]  = v.x; w_[1]  = v.y; w_[2]  = v.z; w_[3]  = v.w;
            v = u4[3*g + 0]; w_[4]  = v.x; w_[5]  = v.y; w_[6]  = v.z; w_[7]  = v.w;
            v = u4[3*g + 1]; w_[8]  = v.x; w_[9]  = v.y; w_[10] = v.z; w_[11] = v.w;
            v = u4[3*g + 2]; w_[12] = v.x; w_[13] = v.y; w_[14] = v.z; w_[15] = v.w;
            v = u4[inext];   w_[16] = v.x; w_[17] = v.y; w_[18] = v.z; w_[19] = v.w;
        }
#define W(k) w_[(k) + 4]

        float c0[4], c1[4], c2[4];   // per-jj results for components r=0,1,2

        // ---- phase 1: MLP1 (weights w1x live in SGPRs, reused 4x) ----
#pragma unroll
        for (int jj = 0; jj < 4; ++jj) {
            const int j = 4 * g + jj;
            float a0, a1, a2;
            mlp_a(W(3*jj - 2), W(3*jj), W(3*jj + 1),
                  w10, b10, w11, b11, w12, b12, a0, a1, a2);
            const float ua = W(3*jj - 1);
            const float ub = W(3*jj + 2);
            c0[jj] = fmaf(W(3*jj), reg[3*j + 1], r0) + fmaf(a2, ub, fmaf(a1, ua, a0));
        }
        // ---- phase 2: MLP2 ----
#pragma unroll
        for (int jj = 0; jj < 4; ++jj) {
            const int j = 4 * g + jj;
            float a0, a1, a2;
            mlp_a(W(3*jj), W(3*jj + 1), W(3*jj + 3),
                  w20, b20, w21, b21, w22, b22, a0, a1, a2);
            const float ua = W(3*jj - 1);
            const float ub = W(3*jj + 2);
            c1[jj] = fmaf(W(3*jj + 1), reg[3*j + 2], r0) + fmaf(a2, ub, fmaf(a1, ua, a0));
        }
        // ---- phase 3: MLP3 ----
#pragma unroll
        for (int jj = 0; jj < 4; ++jj) {
            const int j = 4 * g + jj;
            float d0, d1;
            mlp_b(W(3*jj), W(3*jj + 1), W(3*jj + 3), W(3*jj + 4),
                  w30, b30, w31, b31, w32, b32, d0, d1);
            const float ub = W(3*jj + 2);
            c2[jj] = fmaf(ub, reg[3*j + 3], r0) + fmaf(d1, ub, d0);
        }
#undef W

        // ---- store 12 cols of this group: layout col 12g+3jj+r ----
        o4[3*g + 0] = make_float4(c0[0], c1[0], c2[0], c0[1]);
        o4[3*g + 1] = make_float4(c1[1], c2[1], c0[2], c1[2]);
        o4[3*g + 2] = make_float4(c2[2], c0[3], c1[3], c2[3]);
    }
}

extern "C" void kernel_launch(void* const* d_in, const int* in_sizes, int n_in,
                              void* d_out, int out_size, void* d_ws, size_t ws_size,
                              hipStream_t stream)
{
    // d_in order: t, u, reg, n1_w0, n1_b0, n1_w1, n1_b1, n1_w2, n1_b2,
    //             n2_w0, n2_b0, n2_w1, n2_b1, n2_w2, n2_b2,
    //             n3_w0, n3_b0, n3_w1, n3_b1, n3_w2, n3_b2
    const float* u   = (const float*)d_in[1];
    const float* reg = (const float*)d_in[2];
    const float* w10 = (const float*)d_in[3];
    const float* b10 = (const float*)d_in[4];
    const float* w11 = (const float*)d_in[5];
    const float* b11 = (const float*)d_in[6];
    const float* w12 = (const float*)d_in[7];
    const float* b12 = (const float*)d_in[8];
    const float* w20 = (const float*)d_in[9];
    const float* b20 = (const float*)d_in[10];
    const float* w21 = (const float*)d_in[11];
    const float* b21 = (const float*)d_in[12];
    const float* w22 = (const float*)d_in[13];
    const float* b22 = (const float*)d_in[14];
    const float* w30 = (const float*)d_in[15];
    const float* b30 = (const float*)d_in[16];
    const float* w31 = (const float*)d_in[17];
    const float* b31 = (const float*)d_in[18];
    const float* w32 = (const float*)d_in[19];
    const float* b32 = (const float*)d_in[20];
    float* out = (float*)d_out;

    const int n = in_sizes[1] / 36;  // 1,000,000 rows
    const int block = 256;
    const int grid = (n + block - 1) / block;

    hipLaunchKernelGGL(mixmodel_kernel, dim3(grid), dim3(block), 0, stream,
                       u, reg, w10, b10, w11, b11, w12, b12,
                       w20, b20, w21, b21, w22, b22,
                       w30, b30, w31, b31, w32, b32, out, n);
}

// Round 4
// 154.669 us; speedup vs baseline: 1.0283x; 1.0283x over previous
//
#include <hip/hip_runtime.h>

// ---------------------------------------------------------------------------
// MixModel: out[n,3j+0] = u[3j]*reg[3j+1]+reg[0] + o1.x + o1.y*ua + o1.z*ub
//           out[n,3j+1] = u[3j+1]*reg[3j+2]+reg[0] + o2.x + o2.y*ua + o2.z*ub
//           out[n,3j+2] = u[3j+2]*reg[3j+3]+reg[0] + o3.x + o3.y*ub
// with m=(j+11)%12, p=(j+1)%12:
//   MLP1 in: { u[3m+1], u[3j], u[3j+1] }          (3->3->6->3)
//   MLP2 in: { u[3j], u[3j+1], u[3p] }            (3->3->6->3)
//   MLP3 in: { u[3j], u[3j+1], u[3p], u[3p+1] }   (4->4->6->2)
//   ua = u[3m+2], ub = u[3j+2]
//
// VGPR-tier ladder learned so far (gfx950, block=256):
//   R1  __launch_bounds__(256)   -> VGPR=136, no spill, 127 us
//   R2  __launch_bounds__(256,4) -> VGPR= 64, SPILLS (+240 MB HBM), 158 us
//   R3  (no launch_bounds)       -> VGPR= 64, SPILLS  — default assumes
//       1024-thread blocks / high occupancy target and clamps the allocator!
// R4: R3's small-footprint structure (rolling 20-col window, per-phase
//     mini-loops, immediate stores) + plain __launch_bounds__(256) so the
//     allocator is need-driven (~80-110 VGPR, <=128 tier, no scratch).
// ---------------------------------------------------------------------------

__device__ __forceinline__ float relu_(float x) { return fmaxf(x, 0.0f); }

// MLP 3 -> 3 -> 6 -> 3 (w0:(3,3), w1:(6,3), w2:(3,6), row-major [out][in])
__device__ __forceinline__ void mlp_a(float x0, float x1, float x2,
                                      const float* __restrict__ w0, const float* __restrict__ b0,
                                      const float* __restrict__ w1, const float* __restrict__ b1,
                                      const float* __restrict__ w2, const float* __restrict__ b2,
                                      float& o0, float& o1, float& o2)
{
    float h0[3];
#pragma unroll
    for (int q = 0; q < 3; ++q)
        h0[q] = relu_(fmaf(x2, w0[q*3+2], fmaf(x1, w0[q*3+1], fmaf(x0, w0[q*3+0], b0[q]))));
    float h1[6];
#pragma unroll
    for (int q = 0; q < 6; ++q)
        h1[q] = relu_(fmaf(h0[2], w1[q*3+2], fmaf(h0[1], w1[q*3+1], fmaf(h0[0], w1[q*3+0], b1[q]))));
    float t[3];
#pragma unroll
    for (int q = 0; q < 3; ++q) {
        float a = b2[q];
#pragma unroll
        for (int i = 0; i < 6; ++i) a = fmaf(h1[i], w2[q*6+i], a);
        t[q] = a;
    }
    o0 = t[0]; o1 = t[1]; o2 = t[2];
}

// MLP 4 -> 4 -> 6 -> 2 (w0:(4,4), w1:(6,4), w2:(2,6))
__device__ __forceinline__ void mlp_b(float x0, float x1, float x2, float x3,
                                      const float* __restrict__ w0, const float* __restrict__ b0,
                                      const float* __restrict__ w1, const float* __restrict__ b1,
                                      const float* __restrict__ w2, const float* __restrict__ b2,
                                      float& o0, float& o1)
{
    float h0[4];
#pragma unroll
    for (int q = 0; q < 4; ++q)
        h0[q] = relu_(fmaf(x3, w0[q*4+3], fmaf(x2, w0[q*4+2], fmaf(x1, w0[q*4+1], fmaf(x0, w0[q*4+0], b0[q])))));
    float h1[6];
#pragma unroll
    for (int q = 0; q < 6; ++q)
        h1[q] = relu_(fmaf(h0[3], w1[q*4+3], fmaf(h0[2], w1[q*4+2], fmaf(h0[1], w1[q*4+1], fmaf(h0[0], w1[q*4+0], b1[q])))));
    float t[2];
#pragma unroll
    for (int q = 0; q < 2; ++q) {
        float a = b2[q];
#pragma unroll
        for (int i = 0; i < 6; ++i) a = fmaf(h1[i], w2[q*6+i], a);
        t[q] = a;
    }
    o0 = t[0]; o1 = t[1];
}

__global__ __launch_bounds__(256) void mixmodel_kernel(
    const float* __restrict__ u, const float* __restrict__ reg,
    const float* __restrict__ w10, const float* __restrict__ b10,
    const float* __restrict__ w11, const float* __restrict__ b11,
    const float* __restrict__ w12, const float* __restrict__ b12,
    const float* __restrict__ w20, const float* __restrict__ b20,
    const float* __restrict__ w21, const float* __restrict__ b21,
    const float* __restrict__ w22, const float* __restrict__ b22,
    const float* __restrict__ w30, const float* __restrict__ b30,
    const float* __restrict__ w31, const float* __restrict__ b31,
    const float* __restrict__ w32, const float* __restrict__ b32,
    float* __restrict__ out, int n)
{
    const int tid = blockIdx.x * blockDim.x + threadIdx.x;
    if (tid >= n) return;

    const float4* __restrict__ u4 = reinterpret_cast<const float4*>(u + (size_t)tid * 36);
    float4* __restrict__ o4 = reinterpret_cast<float4*>(out + (size_t)tid * 36);
    const float r0 = reg[0];

#pragma unroll
    for (int g = 0; g < 3; ++g) {
        // ---- rolling window: cols 12g-4 .. 12g+15 (wrapped), W(k)=u[12g+k] ----
        float w_[20];
        {
            const int iprev = (3 * g + 8) % 9;   // wrap: g=0 -> f4 #8
            const int inext = (3 * g + 3) % 9;   // wrap: g=2 -> f4 #0
            float4 v;
            v = u4[iprev];   w_[0]  = v.x; w_[1]  = v.y; w_[2]  = v.z; w_[3]  = v.w;
            v = u4[3*g + 0]; w_[4]  = v.x; w_[5]  = v.y; w_[6]  = v.z; w_[7]  = v.w;
            v = u4[3*g + 1]; w_[8]  = v.x; w_[9]  = v.y; w_[10] = v.z; w_[11] = v.w;
            v = u4[3*g + 2]; w_[12] = v.x; w_[13] = v.y; w_[14] = v.z; w_[15] = v.w;
            v = u4[inext];   w_[16] = v.x; w_[17] = v.y; w_[18] = v.z; w_[19] = v.w;
        }
#define W(k) w_[(k) + 4]

        float c0[4], c1[4], c2[4];   // per-jj results for components r=0,1,2

        // ---- phase 1: MLP1 (weights live in SGPRs, reused 4x) ----
#pragma unroll
        for (int jj = 0; jj < 4; ++jj) {
            const int j = 4 * g + jj;
            float a0, a1, a2;
            mlp_a(W(3*jj - 2), W(3*jj), W(3*jj + 1),
                  w10, b10, w11, b11, w12, b12, a0, a1, a2);
            const float ua = W(3*jj - 1);
            const float ub = W(3*jj + 2);
            c0[jj] = fmaf(W(3*jj), reg[3*j + 1], r0) + fmaf(a2, ub, fmaf(a1, ua, a0));
        }
        // ---- phase 2: MLP2 ----
#pragma unroll
        for (int jj = 0; jj < 4; ++jj) {
            const int j = 4 * g + jj;
            float a0, a1, a2;
            mlp_a(W(3*jj), W(3*jj + 1), W(3*jj + 3),
                  w20, b20, w21, b21, w22, b22, a0, a1, a2);
            const float ua = W(3*jj - 1);
            const float ub = W(3*jj + 2);
            c1[jj] = fmaf(W(3*jj + 1), reg[3*j + 2], r0) + fmaf(a2, ub, fmaf(a1, ua, a0));
        }
        // ---- phase 3: MLP3 ----
#pragma unroll
        for (int jj = 0; jj < 4; ++jj) {
            const int j = 4 * g + jj;
            float d0, d1;
            mlp_b(W(3*jj), W(3*jj + 1), W(3*jj + 3), W(3*jj + 4),
                  w30, b30, w31, b31, w32, b32, d0, d1);
            const float ub = W(3*jj + 2);
            c2[jj] = fmaf(ub, reg[3*j + 3], r0) + fmaf(d1, ub, d0);
        }
#undef W

        // ---- store 12 cols of this group: layout col 12g+3jj+r ----
        o4[3*g + 0] = make_float4(c0[0], c1[0], c2[0], c0[1]);
        o4[3*g + 1] = make_float4(c1[1], c2[1], c0[2], c1[2]);
        o4[3*g + 2] = make_float4(c2[2], c0[3], c1[3], c2[3]);
    }
}

extern "C" void kernel_launch(void* const* d_in, const int* in_sizes, int n_in,
                              void* d_out, int out_size, void* d_ws, size_t ws_size,
                              hipStream_t stream)
{
    // d_in order: t, u, reg, n1_w0, n1_b0, n1_w1, n1_b1, n1_w2, n1_b2,
    //             n2_w0, n2_b0, n2_w1, n2_b1, n2_w2, n2_b2,
    //             n3_w0, n3_b0, n3_w1, n3_b1, n3_w2, n3_b2
    const float* u   = (const float*)d_in[1];
    const float* reg = (const float*)d_in[2];
    const float* w10 = (const float*)d_in[3];
    const float* b10 = (const float*)d_in[4];
    const float* w11 = (const float*)d_in[5];
    const float* b11 = (const float*)d_in[6];
    const float* w12 = (const float*)d_in[7];
    const float* b12 = (const float*)d_in[8];
    const float* w20 = (const float*)d_in[9];
    const float* b20 = (const float*)d_in[10];
    const float* w21 = (const float*)d_in[11];
    const float* b21 = (const float*)d_in[12];
    const float* w22 = (const float*)d_in[13];
    const float* b22 = (const float*)d_in[14];
    const float* w30 = (const float*)d_in[15];
    const float* b30 = (const float*)d_in[16];
    const float* w31 = (const float*)d_in[17];
    const float* b31 = (const float*)d_in[18];
    const float* w32 = (const float*)d_in[19];
    const float* b32 = (const float*)d_in[20];
    float* out = (float*)d_out;

    const int n = in_sizes[1] / 36;  // 1,000,000 rows
    const int block = 256;
    const int grid = (n + block - 1) / block;

    hipLaunchKernelGGL(mixmodel_kernel, dim3(grid), dim3(block), 0, stream,
                       u, reg, w10, b10, w11, b11, w12, b12,
                       w20, b20, w21, b21, w22, b22,
                       w30, b30, w31, b31, w32, b32, out, n);
}

// Round 6
// 76.072 us; speedup vs baseline: 2.0907x; 2.0332x over previous
//
#include <hip/hip_runtime.h>

// ---------------------------------------------------------------------------
// MixModel: out[row,3j+0] = u[3j]*reg[3j+1]+reg[0] + o1.x + o1.y*ua + o1.z*ub
//           out[row,3j+1] = u[3j+1]*reg[3j+2]+reg[0] + o2.x + o2.y*ua + o2.z*ub
//           out[row,3j+2] = u[3j+2]*reg[3j+3]+reg[0] + o3.x + o3.y*ub
// with m=(j+11)%12, p=(j+1)%12 (all u-columns mod 36):
//   MLP1 in: { u[3m+1], u[3j], u[3j+1] }          (3->3->6->3)
//   MLP2 in: { u[3j], u[3j+1], u[3p] }            (3->3->6->3)
//   MLP3 in: { u[3j], u[3j+1], u[3p], u[3p+1] }   (4->4->6->2)
//   ua = u[3m+2], ub = u[3j+2]
//
// Ladder:
//   R1 1thr/row lb(256)  VGPR=136 no-spill 127us | R2 lb(256,4) 64 SPILL 158
//   R3 no-lb 64 SPILL 159 | R4 window lb(256) 76 SPILL 155
//   R5 3thr/row: FAILED — f4 window index 3r+8+t in 8..18 wrapped only ONCE
//      (idx=18 -> 9 = next row's cols). R6 = R5 + double wrap.
// Thread (row,r): output cols 12r..12r+11 from 20-col window
// W(k)=u[row,(12r+k)%36], 5 aligned float4 loads. ~45 live VGPRs -> fits the
// 64 tier the allocator insists on; stores contiguous 48B per lane.
// ---------------------------------------------------------------------------

__device__ __forceinline__ float relu_(float x) { return fmaxf(x, 0.0f); }

// MLP 3 -> 3 -> 6 -> 3 (w0:(3,3), w1:(6,3), w2:(3,6), row-major [out][in])
__device__ __forceinline__ void mlp_a(float x0, float x1, float x2,
                                      const float* __restrict__ w0, const float* __restrict__ b0,
                                      const float* __restrict__ w1, const float* __restrict__ b1,
                                      const float* __restrict__ w2, const float* __restrict__ b2,
                                      float& o0, float& o1, float& o2)
{
    float h0[3];
#pragma unroll
    for (int q = 0; q < 3; ++q)
        h0[q] = relu_(fmaf(x2, w0[q*3+2], fmaf(x1, w0[q*3+1], fmaf(x0, w0[q*3+0], b0[q]))));
    float h1[6];
#pragma unroll
    for (int q = 0; q < 6; ++q)
        h1[q] = relu_(fmaf(h0[2], w1[q*3+2], fmaf(h0[1], w1[q*3+1], fmaf(h0[0], w1[q*3+0], b1[q]))));
    float t[3];
#pragma unroll
    for (int q = 0; q < 3; ++q) {
        float a = b2[q];
#pragma unroll
        for (int i = 0; i < 6; ++i) a = fmaf(h1[i], w2[q*6+i], a);
        t[q] = a;
    }
    o0 = t[0]; o1 = t[1]; o2 = t[2];
}

// MLP 4 -> 4 -> 6 -> 2 (w0:(4,4), w1:(6,4), w2:(2,6))
__device__ __forceinline__ void mlp_b(float x0, float x1, float x2, float x3,
                                      const float* __restrict__ w0, const float* __restrict__ b0,
                                      const float* __restrict__ w1, const float* __restrict__ b1,
                                      const float* __restrict__ w2, const float* __restrict__ b2,
                                      float& o0, float& o1)
{
    float h0[4];
#pragma unroll
    for (int q = 0; q < 4; ++q)
        h0[q] = relu_(fmaf(x3, w0[q*4+3], fmaf(x2, w0[q*4+2], fmaf(x1, w0[q*4+1], fmaf(x0, w0[q*4+0], b0[q])))));
    float h1[6];
#pragma unroll
    for (int q = 0; q < 6; ++q)
        h1[q] = relu_(fmaf(h0[3], w1[q*4+3], fmaf(h0[2], w1[q*4+2], fmaf(h0[1], w1[q*4+1], fmaf(h0[0], w1[q*4+0], b1[q])))));
    float t[2];
#pragma unroll
    for (int q = 0; q < 2; ++q) {
        float a = b2[q];
#pragma unroll
        for (int i = 0; i < 6; ++i) a = fmaf(h1[i], w2[q*6+i], a);
        t[q] = a;
    }
    o0 = t[0]; o1 = t[1];
}

__global__ __launch_bounds__(256) void mixmodel_kernel(
    const float* __restrict__ u, const float* __restrict__ reg,
    const float* __restrict__ w10, const float* __restrict__ b10,
    const float* __restrict__ w11, const float* __restrict__ b11,
    const float* __restrict__ w12, const float* __restrict__ b12,
    const float* __restrict__ w20, const float* __restrict__ b20,
    const float* __restrict__ w21, const float* __restrict__ b21,
    const float* __restrict__ w22, const float* __restrict__ b22,
    const float* __restrict__ w30, const float* __restrict__ b30,
    const float* __restrict__ w31, const float* __restrict__ b31,
    const float* __restrict__ w32, const float* __restrict__ b32,
    float* __restrict__ out, int n3)
{
    const int tid = blockIdx.x * blockDim.x + threadIdx.x;
    if (tid >= n3) return;
    const int row = tid / 3;          // magic-multiply division
    const int r   = tid - 3 * row;    // 0..2 -> output cols 12r..12r+11

    const float4* __restrict__ u4 = reinterpret_cast<const float4*>(u + (size_t)row * 36);

    // ---- 20-col window: W(k) = u[row, (12r+k) mod 36], k = -4..15 ----
    float w_[20];
#pragma unroll
    for (int t = 0; t < 5; ++t) {
        int idx = 3 * r + 8 + t;               // 8..18
        if (idx >= 9) idx -= 9;                // 0..9  (18 -> 9!)
        if (idx >= 9) idx -= 9;                // 0..8  — R5's bug was missing this
        const float4 v = u4[idx];
        w_[4*t+0] = v.x; w_[4*t+1] = v.y; w_[4*t+2] = v.z; w_[4*t+3] = v.w;
    }
#define W(k) w_[(k) + 4]

    const float r0 = reg[0];
    const float* __restrict__ rb = reg + 12 * r;   // rb[3jj+1..3] per jj

    float c0[4], c1[4], c2[4];

    // ---- phase 1: MLP1 (weights uniform -> SGPRs, reused 4x) ----
#pragma unroll
    for (int jj = 0; jj < 4; ++jj) {
        float a0, a1, a2;
        mlp_a(W(3*jj - 2), W(3*jj), W(3*jj + 1),
              w10, b10, w11, b11, w12, b12, a0, a1, a2);
        const float ua = W(3*jj - 1);
        const float ub = W(3*jj + 2);
        c0[jj] = fmaf(W(3*jj), rb[3*jj + 1], r0) + fmaf(a2, ub, fmaf(a1, ua, a0));
    }
    // ---- phase 2: MLP2 ----
#pragma unroll
    for (int jj = 0; jj < 4; ++jj) {
        float a0, a1, a2;
        mlp_a(W(3*jj), W(3*jj + 1), W(3*jj + 3),
              w20, b20, w21, b21, w22, b22, a0, a1, a2);
        const float ua = W(3*jj - 1);
        const float ub = W(3*jj + 2);
        c1[jj] = fmaf(W(3*jj + 1), rb[3*jj + 2], r0) + fmaf(a2, ub, fmaf(a1, ua, a0));
    }
    // ---- phase 3: MLP3 ----
#pragma unroll
    for (int jj = 0; jj < 4; ++jj) {
        float d0, d1;
        mlp_b(W(3*jj), W(3*jj + 1), W(3*jj + 3), W(3*jj + 4),
              w30, b30, w31, b31, w32, b32, d0, d1);
        const float ub = W(3*jj + 2);
        c2[jj] = fmaf(ub, rb[3*jj + 3], r0) + fmaf(d1, ub, d0);
    }
#undef W

    // ---- store 12 contiguous cols at out[row, 12r .. 12r+11] ----
    float4* __restrict__ o4 = reinterpret_cast<float4*>(out + (size_t)row * 36 + 12 * r);
    o4[0] = make_float4(c0[0], c1[0], c2[0], c0[1]);
    o4[1] = make_float4(c1[1], c2[1], c0[2], c1[2]);
    o4[2] = make_float4(c2[2], c0[3], c1[3], c2[3]);
}

extern "C" void kernel_launch(void* const* d_in, const int* in_sizes, int n_in,
                              void* d_out, int out_size, void* d_ws, size_t ws_size,
                              hipStream_t stream)
{
    // d_in order: t, u, reg, n1_w0, n1_b0, n1_w1, n1_b1, n1_w2, n1_b2,
    //             n2_w0, n2_b0, n2_w1, n2_b1, n2_w2, n2_b2,
    //             n3_w0, n3_b0, n3_w1, n3_b1, n3_w2, n3_b2
    const float* u   = (const float*)d_in[1];
    const float* reg = (const float*)d_in[2];
    const float* w10 = (const float*)d_in[3];
    const float* b10 = (const float*)d_in[4];
    const float* w11 = (const float*)d_in[5];
    const float* b11 = (const float*)d_in[6];
    const float* w12 = (const float*)d_in[7];
    const float* b12 = (const float*)d_in[8];
    const float* w20 = (const float*)d_in[9];
    const float* b20 = (const float*)d_in[10];
    const float* w21 = (const float*)d_in[11];
    const float* b21 = (const float*)d_in[12];
    const float* w22 = (const float*)d_in[13];
    const float* b22 = (const float*)d_in[14];
    const float* w30 = (const float*)d_in[15];
    const float* b30 = (const float*)d_in[16];
    const float* w31 = (const float*)d_in[17];
    const float* b31 = (const float*)d_in[18];
    const float* w32 = (const float*)d_in[19];
    const float* b32 = (const float*)d_in[20];
    float* out = (float*)d_out;

    const int n  = in_sizes[1] / 36;   // 1,000,000 rows
    const int n3 = 3 * n;              // 3 threads per row
    const int block = 256;
    const int grid = (n3 + block - 1) / block;

    hipLaunchKernelGGL(mixmodel_kernel, dim3(grid), dim3(block), 0, stream,
                       u, reg, w10, b10, w11, b11, w12, b12,
                       w20, b20, w21, b21, w22, b22,
                       w30, b30, w31, b31, w32, b32, out, n3);
}

// Round 7
// 74.843 us; speedup vs baseline: 2.1250x; 1.0164x over previous
//
#include <hip/hip_runtime.h>

// ---------------------------------------------------------------------------
// MixModel, 3 threads/row (thread r -> output cols 12r..12r+11).
// R6: VGPR=60 no-spill, 76us, VALUBusy 75% -> VALU-issue-bound.
// R7: pack the 4 independent jj iterations as 2x float2 and use
//     __builtin_elementwise_fma so LLVM selects v_pk_fma_f32
//     (gfx950 has FeaturePackedFP32Ops). Halves MLP VALU inst count.
//     Math is bit-identical fp32.
// Ladder: R1 136VGPR 127us | R2/R3/R4 spills 155-159us | R6 60VGPR 76us.
// Spill signature to watch: WRITE_SIZE >> 140,625 KB.
// ---------------------------------------------------------------------------

typedef float f2 __attribute__((ext_vector_type(2)));

__device__ __forceinline__ f2 splat2(float x) { f2 v; v.x = x; v.y = x; return v; }
__device__ __forceinline__ f2 mk2(float a, float b) { f2 v; v.x = a; v.y = b; return v; }
__device__ __forceinline__ f2 fma2(f2 a, f2 b, f2 c) { return __builtin_elementwise_fma(a, b, c); }
__device__ __forceinline__ f2 relu2(f2 a) { return __builtin_elementwise_max(a, splat2(0.0f)); }

// Packed MLP 3->3->6->3 for a pair of positions. Biases folded into first fma.
__device__ __forceinline__ void mlp_a2(f2 x0, f2 x1, f2 x2,
                                       const float* __restrict__ w0, const float* __restrict__ b0,
                                       const float* __restrict__ w1, const float* __restrict__ b1,
                                       const float* __restrict__ w2, const float* __restrict__ b2,
                                       f2& o0, f2& o1, f2& o2)
{
    f2 h0[3];
#pragma unroll
    for (int q = 0; q < 3; ++q) {
        f2 a = fma2(x0, splat2(w0[q*3+0]), splat2(b0[q]));
        a = fma2(x1, splat2(w0[q*3+1]), a);
        a = fma2(x2, splat2(w0[q*3+2]), a);
        h0[q] = relu2(a);
    }
    f2 h1[6];
#pragma unroll
    for (int q = 0; q < 6; ++q) {
        f2 a = fma2(h0[0], splat2(w1[q*3+0]), splat2(b1[q]));
        a = fma2(h0[1], splat2(w1[q*3+1]), a);
        a = fma2(h0[2], splat2(w1[q*3+2]), a);
        h1[q] = relu2(a);
    }
    f2 t[3];
#pragma unroll
    for (int q = 0; q < 3; ++q) {
        f2 a = fma2(h1[0], splat2(w2[q*6+0]), splat2(b2[q]));
#pragma unroll
        for (int i = 1; i < 6; ++i) a = fma2(h1[i], splat2(w2[q*6+i]), a);
        t[q] = a;
    }
    o0 = t[0]; o1 = t[1]; o2 = t[2];
}

// Packed MLP 4->4->6->2 for a pair of positions.
__device__ __forceinline__ void mlp_b2(f2 x0, f2 x1, f2 x2, f2 x3,
                                       const float* __restrict__ w0, const float* __restrict__ b0,
                                       const float* __restrict__ w1, const float* __restrict__ b1,
                                       const float* __restrict__ w2, const float* __restrict__ b2,
                                       f2& o0, f2& o1)
{
    f2 h0[4];
#pragma unroll
    for (int q = 0; q < 4; ++q) {
        f2 a = fma2(x0, splat2(w0[q*4+0]), splat2(b0[q]));
        a = fma2(x1, splat2(w0[q*4+1]), a);
        a = fma2(x2, splat2(w0[q*4+2]), a);
        a = fma2(x3, splat2(w0[q*4+3]), a);
        h0[q] = relu2(a);
    }
    f2 h1[6];
#pragma unroll
    for (int q = 0; q < 6; ++q) {
        f2 a = fma2(h0[0], splat2(w1[q*4+0]), splat2(b1[q]));
        a = fma2(h0[1], splat2(w1[q*4+1]), a);
        a = fma2(h0[2], splat2(w1[q*4+2]), a);
        a = fma2(h0[3], splat2(w1[q*4+3]), a);
        h1[q] = relu2(a);
    }
    f2 t[2];
#pragma unroll
    for (int q = 0; q < 2; ++q) {
        f2 a = fma2(h1[0], splat2(w2[q*6+0]), splat2(b2[q]));
#pragma unroll
        for (int i = 1; i < 6; ++i) a = fma2(h1[i], splat2(w2[q*6+i]), a);
        t[q] = a;
    }
    o0 = t[0]; o1 = t[1];
}

__global__ __launch_bounds__(256) void mixmodel_kernel(
    const float* __restrict__ u, const float* __restrict__ reg,
    const float* __restrict__ w10, const float* __restrict__ b10,
    const float* __restrict__ w11, const float* __restrict__ b11,
    const float* __restrict__ w12, const float* __restrict__ b12,
    const float* __restrict__ w20, const float* __restrict__ b20,
    const float* __restrict__ w21, const float* __restrict__ b21,
    const float* __restrict__ w22, const float* __restrict__ b22,
    const float* __restrict__ w30, const float* __restrict__ b30,
    const float* __restrict__ w31, const float* __restrict__ b31,
    const float* __restrict__ w32, const float* __restrict__ b32,
    float* __restrict__ out, int n3)
{
    const int tid = blockIdx.x * blockDim.x + threadIdx.x;
    if (tid >= n3) return;
    const int row = tid / 3;
    const int r   = tid - 3 * row;     // 0..2 -> output cols 12r..12r+11

    const float4* __restrict__ u4 = reinterpret_cast<const float4*>(u + (size_t)row * 36);

    // ---- 20-col window: W(k) = u[row, (12r+k) mod 36], k = -4..15 ----
    float w_[20];
#pragma unroll
    for (int t = 0; t < 5; ++t) {
        int idx = 3 * r + 8 + t;               // 8..18
        if (idx >= 9) idx -= 9;                // 0..9
        if (idx >= 9) idx -= 9;                // 0..8 (double wrap — R5 bug)
        const float4 v = u4[idx];
        w_[4*t+0] = v.x; w_[4*t+1] = v.y; w_[4*t+2] = v.z; w_[4*t+3] = v.w;
    }
#define W(k) w_[(k) + 4]

    const float r0 = reg[0];
    const float* __restrict__ rb = reg + 12 * r;
    const f2 r02 = splat2(r0);

    f2 c0[2], c1[2], c2[2];   // pair P covers jj = 2P, 2P+1

    // ---- phase 1: MLP1 -> c0 ----
#pragma unroll
    for (int P = 0; P < 2; ++P) {
        const int q = 6 * P;   // 3*jj for jj=2P
        f2 a0, a1, a2;
        mlp_a2(mk2(W(q - 2), W(q + 1)), mk2(W(q), W(q + 3)), mk2(W(q + 1), W(q + 4)),
               w10, b10, w11, b11, w12, b12, a0, a1, a2);
        const f2 ua = mk2(W(q - 1), W(q + 2));
        const f2 ub = mk2(W(q + 2), W(q + 5));
        const f2 rv = mk2(rb[q + 1], rb[q + 4]);
        const f2 uv = mk2(W(q), W(q + 3));
        c0[P] = fma2(uv, rv, r02) + fma2(a2, ub, fma2(a1, ua, a0));
    }
    // ---- phase 2: MLP2 -> c1 ----
#pragma unroll
    for (int P = 0; P < 2; ++P) {
        const int q = 6 * P;
        f2 a0, a1, a2;
        mlp_a2(mk2(W(q), W(q + 3)), mk2(W(q + 1), W(q + 4)), mk2(W(q + 3), W(q + 6)),
               w20, b20, w21, b21, w22, b22, a0, a1, a2);
        const f2 ua = mk2(W(q - 1), W(q + 2));
        const f2 ub = mk2(W(q + 2), W(q + 5));
        const f2 rv = mk2(rb[q + 2], rb[q + 5]);
        const f2 uv = mk2(W(q + 1), W(q + 4));
        c1[P] = fma2(uv, rv, r02) + fma2(a2, ub, fma2(a1, ua, a0));
    }
    // ---- phase 3: MLP3 -> c2 ----
#pragma unroll
    for (int P = 0; P < 2; ++P) {
        const int q = 6 * P;
        f2 d0, d1;
        mlp_b2(mk2(W(q), W(q + 3)), mk2(W(q + 1), W(q + 4)),
               mk2(W(q + 3), W(q + 6)), mk2(W(q + 4), W(q + 7)),
               w30, b30, w31, b31, w32, b32, d0, d1);
        const f2 ub = mk2(W(q + 2), W(q + 5));
        const f2 rv = mk2(rb[q + 3], rb[q + 6]);
        c2[P] = fma2(ub, rv, r02) + fma2(d1, ub, d0);
    }
#undef W

    // ---- store 12 contiguous cols at out[row, 12r..12r+11] ----
    // col order per jj: (c0, c1, c2); pair P holds jj=2P (.x), 2P+1 (.y)
    float4* __restrict__ o4 = reinterpret_cast<float4*>(out + (size_t)row * 36 + 12 * r);
    o4[0] = make_float4(c0[0].x, c1[0].x, c2[0].x, c0[0].y);
    o4[1] = make_float4(c1[0].y, c2[0].y, c0[1].x, c1[1].x);
    o4[2] = make_float4(c2[1].x, c0[1].y, c1[1].y, c2[1].y);
}

extern "C" void kernel_launch(void* const* d_in, const int* in_sizes, int n_in,
                              void* d_out, int out_size, void* d_ws, size_t ws_size,
                              hipStream_t stream)
{
    const float* u   = (const float*)d_in[1];
    const float* reg = (const float*)d_in[2];
    const float* w10 = (const float*)d_in[3];
    const float* b10 = (const float*)d_in[4];
    const float* w11 = (const float*)d_in[5];
    const float* b11 = (const float*)d_in[6];
    const float* w12 = (const float*)d_in[7];
    const float* b12 = (const float*)d_in[8];
    const float* w20 = (const float*)d_in[9];
    const float* b20 = (const float*)d_in[10];
    const float* w21 = (const float*)d_in[11];
    const float* b21 = (const float*)d_in[12];
    const float* w22 = (const float*)d_in[13];
    const float* b22 = (const float*)d_in[14];
    const float* w30 = (const float*)d_in[15];
    const float* b30 = (const float*)d_in[16];
    const float* w31 = (const float*)d_in[17];
    const float* b31 = (const float*)d_in[18];
    const float* w32 = (const float*)d_in[19];
    const float* b32 = (const float*)d_in[20];
    float* out = (float*)d_out;

    const int n  = in_sizes[1] / 36;   // 1,000,000 rows
    const int n3 = 3 * n;              // 3 threads per row
    const int block = 256;
    const int grid = (n3 + block - 1) / block;

    hipLaunchKernelGGL(mixmodel_kernel, dim3(grid), dim3(block), 0, stream,
                       u, reg, w10, b10, w11, b11, w12, b12,
                       w20, b20, w21, b21, w22, b22,
                       w30, b30, w31, b31, w32, b32, out, n3);
}